// Round 10
// baseline (191.155 us; speedup 1.0000x reference)
//
#include <hip/hip_runtime.h>
#include <hip/hip_bf16.h>

// Problem constants
#define D 128
#define EPS 1e-5f

typedef __bf16 bf16x8 __attribute__((ext_vector_type(8)));
typedef __bf16 bf16x4 __attribute__((ext_vector_type(4)));
typedef float  f32x4  __attribute__((ext_vector_type(4)));

// ---------------------------------------------------------------------------
// Kernel 1 (prep): convert W (f32) -> Wb (bf16, 32 KB) AND zero counts.
// ---------------------------------------------------------------------------
__global__ __launch_bounds__(256) void prep_kernel(
    const float* __restrict__ W, __bf16* __restrict__ Wb,
    int* __restrict__ counts, int n)
{
    const int tid = blockIdx.x * 256 + threadIdx.x;   // 0..4095

    if (tid < 4096) {
        float4 v = ((const float4*)W)[tid];
        bf16x4 h;
        h[0] = (__bf16)v.x; h[1] = (__bf16)v.y;
        h[2] = (__bf16)v.z; h[3] = (__bf16)v.w;
        ((bf16x4*)Wb)[tid] = h;
    }
    for (int i = tid; i < n; i += 4096)
        counts[i] = 0;
}

// ---------------------------------------------------------------------------
// Kernel 2: dst-degree histogram.
// ---------------------------------------------------------------------------
__global__ __launch_bounds__(256) void hist_kernel(
    const int* __restrict__ e, int* __restrict__ counts, int E)
{
    int i = blockIdx.x * 256 + threadIdx.x;
    if (i < E) {
        int2 ed = ((const int2*)e)[i];
        atomicAdd(&counts[ed.y], 1);
    }
}

// ---------------------------------------------------------------------------
// Kernel 3: y_bf16 = relu(x @ W^T + b) via MFMA.
// Compute identical to round 9 (16x64 wave tiles, hoisted loads, no staging).
// NEW: epilogue stages the block's 32x128 bf16 tile in LDS ([32][136] pad ->
// <=2-way bank aliasing both sides), then stores y fully coalesced: thread t
// writes 32 B of row (t>>3); a wave covers 8 rows x 256 B contiguous.
// This replaces 16 scattered 2 B stores/thread (3x HBM write amplification,
// WRITE_SIZE 29.9 MB for 10.2 MB of y in round 8) with clean float4 pairs.
// C/D layout (m89-verified): col = lane&15, row = (lane>>4)*4 + reg.
// ---------------------------------------------------------------------------
__global__ __launch_bounds__(256) void gemm_kernel(
    const float* __restrict__ x, const __bf16* __restrict__ Wb,
    const float* __restrict__ b, __bf16* __restrict__ y, int n)
{
    __shared__ __attribute__((aligned(16))) __bf16 ys[32][136];

    const int tid  = threadIdx.x;
    const int w    = tid >> 6;
    const int l    = tid & 63;
    const int lr   = l & 15;
    const int lk   = l >> 4;                    // 0..3
    const int brow0 = (w & 1) * 16;             // block-local row base of wave
    const int row0 = blockIdx.x * 32 + brow0;   // global row base of wave
    const int col0 = (w >> 1) * 64;

    int ar = row0 + lr;
    if (ar >= n) ar = n - 1;                    // clamp; stores are guarded
    const float* xr = x + (size_t)ar * D;

    // ---- issue ALL loads up front (independent; deep MLP) ----
    float4 xv[8];
#pragma unroll
    for (int ks = 0; ks < 4; ks++) {
        xv[2 * ks]     = *(const float4*)(xr + ks * 32 + lk * 8);
        xv[2 * ks + 1] = *(const float4*)(xr + ks * 32 + lk * 8 + 4);
    }
    bf16x8 wf[4][4];
#pragma unroll
    for (int ct = 0; ct < 4; ct++)
#pragma unroll
        for (int ks = 0; ks < 4; ks++)
            wf[ct][ks] = *(const bf16x8*)
                (Wb + (size_t)(col0 + ct * 16 + lr) * D + ks * 32 + lk * 8);

    // ---- convert a-frags in registers ----
    bf16x8 a[4];
#pragma unroll
    for (int ks = 0; ks < 4; ks++) {
        bf16x8 t;
        t[0] = (__bf16)xv[2 * ks].x;     t[1] = (__bf16)xv[2 * ks].y;
        t[2] = (__bf16)xv[2 * ks].z;     t[3] = (__bf16)xv[2 * ks].w;
        t[4] = (__bf16)xv[2 * ks + 1].x; t[5] = (__bf16)xv[2 * ks + 1].y;
        t[6] = (__bf16)xv[2 * ks + 1].z; t[7] = (__bf16)xv[2 * ks + 1].w;
        a[ks] = t;
    }

    // ---- MFMA chain (4 independent accumulators) ----
    f32x4 acc[4];
#pragma unroll
    for (int ct = 0; ct < 4; ct++) acc[ct] = (f32x4){0.f, 0.f, 0.f, 0.f};
#pragma unroll
    for (int ks = 0; ks < 4; ks++)
#pragma unroll
        for (int ct = 0; ct < 4; ct++)
            acc[ct] = __builtin_amdgcn_mfma_f32_16x16x32_bf16(
                a[ks], wf[ct][ks], acc[ct], 0, 0, 0);

    // ---- bias + relu into LDS tile ----
#pragma unroll
    for (int ct = 0; ct < 4; ct++) {
        const int c = col0 + ct * 16 + lr;
        const float bias = b[c];
#pragma unroll
        for (int reg = 0; reg < 4; reg++)
            ys[brow0 + lk * 4 + reg][c] = (__bf16)fmaxf(acc[ct][reg] + bias, 0.f);
    }
    __syncthreads();

    // ---- coalesced store: 32 rows x 256 B; thread t -> row t>>3, 32 B seg ----
    {
        const int r = tid >> 3;
        const int s = tid & 7;
        const int gr = blockIdx.x * 32 + r;
        if (gr < n) {
            const float4* src = (const float4*)&ys[r][s * 16];
            float4 v0 = src[0];
            float4 v1 = src[1];
            float4* dst = (float4*)(y + (size_t)gr * D + s * 16);
            dst[0] = v0;
            dst[1] = v1;
        }
    }
}

// ---------------------------------------------------------------------------
// CSR build, step 2a: per-block exclusive scan (256 elems/block).
// ---------------------------------------------------------------------------
__global__ __launch_bounds__(256) void scan_partial_kernel(
    const int* __restrict__ counts, int* __restrict__ row_start,
    int* __restrict__ partials, int n)
{
    __shared__ int s[256];
    const int tid = threadIdx.x;
    const int i = blockIdx.x * 256 + tid;
    int v = (i < n) ? counts[i] : 0;
    s[tid] = v;
    __syncthreads();
    for (int off = 1; off < 256; off <<= 1) {
        int add = (tid >= off) ? s[tid - off] : 0;
        __syncthreads();
        s[tid] += add;
        __syncthreads();
    }
    if (i < n) row_start[i] = s[tid] - v;        // relative exclusive
    if (tid == 255) partials[blockIdx.x] = s[255];
}

// ---------------------------------------------------------------------------
// CSR build, step 2b: every block re-scans partials in LDS, takes its own
// exclusive prefix, adds to its rows. Writes sentinel row_start[n] = E.
// ---------------------------------------------------------------------------
__global__ __launch_bounds__(256) void scan_add_kernel(
    int* __restrict__ row_start, const int* __restrict__ partials,
    int* __restrict__ cursor, int n, int nb)
{
    __shared__ int s[256];
    const int tid = threadIdx.x;
    int v = (tid < nb) ? partials[tid] : 0;
    s[tid] = v;
    __syncthreads();
    for (int off = 1; off < 256; off <<= 1) {
        int add = (tid >= off) ? s[tid - off] : 0;
        __syncthreads();
        s[tid] += add;
        __syncthreads();
    }
    int off0 = (blockIdx.x == 0) ? 0 : s[blockIdx.x - 1];  // exclusive prefix

    if (blockIdx.x == 0 && tid == 0)
        row_start[n] = s[255];                    // sentinel: total edge count

    int i = blockIdx.x * 256 + tid;
    if (i < n) {
        int val = row_start[i] + off0;
        row_start[i] = val;
        cursor[i]    = val;
    }
}

// ---------------------------------------------------------------------------
// CSR build, step 3: place each edge's src (uint16: n < 65536) into its
// dst segment. Order nondeterministic; max is order-independent -> bit-exact.
// ---------------------------------------------------------------------------
__global__ __launch_bounds__(256) void place_kernel(
    const int* __restrict__ e, int* __restrict__ cursor,
    unsigned short* __restrict__ sorted_src, int E)
{
    int i = blockIdx.x * 256 + threadIdx.x;
    if (i < E) {
        int2 ed = ((const int2*)e)[i];             // (src, dst)
        int pos = atomicAdd(&cursor[ed.y], 1);
        sorted_src[pos] = (unsigned short)ed.x;
    }
}

// ---------------------------------------------------------------------------
// Kernel 7 (fused): per-dst gather-max over CSR segment (y in bf16), then
// h = x + agg; RMSNorm; out = h * rsqrt(mean(h^2)+eps) * g + rb.
// One 64-lane wave per row; lane holds one uint = 2 bf16 (256 B/row gather).
// bf16 -> f32 is an exact <<16; max over non-negative bf16 is exact.
// ---------------------------------------------------------------------------
__global__ __launch_bounds__(256) void seg_max_finalize_kernel(
    const int* __restrict__ row_start, const unsigned short* __restrict__ ssrc,
    const unsigned int* __restrict__ ybu, const float* __restrict__ x,
    const float* __restrict__ g, const float* __restrict__ rb,
    float* __restrict__ out, int n)
{
    int row  = blockIdx.x * 4 + (threadIdx.x >> 6);
    int lane = threadIdx.x & 63;
    if (row >= n) return;

    const int start = row_start[row];
    const int end   = row_start[row + 1];

    float mx = 0.f, my = 0.f;
    int k = start;
    const int end8 = start + ((end - start) & ~7);
    for (; k < end8; k += 8) {
        int s0 = ssrc[k + 0], s1 = ssrc[k + 1], s2 = ssrc[k + 2], s3 = ssrc[k + 3];
        int s4 = ssrc[k + 4], s5 = ssrc[k + 5], s6 = ssrc[k + 6], s7 = ssrc[k + 7];
        unsigned int u0 = ybu[(size_t)s0 * 64 + lane];
        unsigned int u1 = ybu[(size_t)s1 * 64 + lane];
        unsigned int u2 = ybu[(size_t)s2 * 64 + lane];
        unsigned int u3 = ybu[(size_t)s3 * 64 + lane];
        unsigned int u4 = ybu[(size_t)s4 * 64 + lane];
        unsigned int u5 = ybu[(size_t)s5 * 64 + lane];
        unsigned int u6 = ybu[(size_t)s6 * 64 + lane];
        unsigned int u7 = ybu[(size_t)s7 * 64 + lane];
        mx = fmaxf(mx, fmaxf(fmaxf(__uint_as_float(u0 << 16), __uint_as_float(u1 << 16)),
                             fmaxf(__uint_as_float(u2 << 16), __uint_as_float(u3 << 16))));
        mx = fmaxf(mx, fmaxf(fmaxf(__uint_as_float(u4 << 16), __uint_as_float(u5 << 16)),
                             fmaxf(__uint_as_float(u6 << 16), __uint_as_float(u7 << 16))));
        my = fmaxf(my, fmaxf(fmaxf(__uint_as_float(u0 & 0xffff0000u), __uint_as_float(u1 & 0xffff0000u)),
                             fmaxf(__uint_as_float(u2 & 0xffff0000u), __uint_as_float(u3 & 0xffff0000u))));
        my = fmaxf(my, fmaxf(fmaxf(__uint_as_float(u4 & 0xffff0000u), __uint_as_float(u5 & 0xffff0000u)),
                             fmaxf(__uint_as_float(u6 & 0xffff0000u), __uint_as_float(u7 & 0xffff0000u))));
    }
    for (; k < end; k++) {
        int s0 = ssrc[k];
        unsigned int u0 = ybu[(size_t)s0 * 64 + lane];
        mx = fmaxf(mx, __uint_as_float(u0 << 16));
        my = fmaxf(my, __uint_as_float(u0 & 0xffff0000u));
    }

    float2 xv = ((const float2*)(x + (size_t)row * D))[lane];
    float hx = xv.x + mx;
    float hy = xv.y + my;

    float ss = hx * hx + hy * hy;
#pragma unroll
    for (int off = 1; off < 64; off <<= 1) ss += __shfl_xor(ss, off);

    float inv = rsqrtf(ss * (1.0f / (float)D) + EPS);

    float2 gv = ((const float2*)g)[lane];
    float2 rv = ((const float2*)rb)[lane];
    float2 o  = make_float2(hx * inv * gv.x + rv.x,
                            hy * inv * gv.y + rv.y);
    ((float2*)(out + (size_t)row * D))[lane] = o;
}

// ---------------------------------------------------------------------------
extern "C" void kernel_launch(void* const* d_in, const int* in_sizes, int n_in,
                              void* d_out, int out_size, void* d_ws, size_t ws_size,
                              hipStream_t stream)
{
    const float* x  = (const float*)d_in[0];
    const int*   e  = (const int*)  d_in[1];
    const float* W  = (const float*)d_in[2];
    const float* b  = (const float*)d_in[3];
    const float* g  = (const float*)d_in[4];
    const float* rb = (const float*)d_in[5];
    float* out = (float*)d_out;

    const int n = in_sizes[0] / D;     // 40000 nodes
    const int E = in_sizes[1] / 2;     // 640000 edges

    // Workspace layout (256B-aligned offsets)
    char* ws = (char*)d_ws;
    __bf16* y        = (__bf16*)(ws);                      // 10,240,000 B
    int*   counts    = (int*)  (ws + 10240000);            //    160,000 B
    int*   row_start = (int*)  (ws + 10400000);            //    160,004 B (+sentinel)
    int*   cursor    = (int*)  (ws + 10560256);            //    160,000 B
    unsigned short* sorted_src = (unsigned short*)(ws + 10720256); // 1,280,000 B
    int*   partials  = (int*)  (ws + 12000256);            //      1,024 B
    __bf16* Wb       = (__bf16*)(ws + 12001536);           //     32,768 B

    const int nb = (n + 255) / 256;                 // 157 (must be <= 256)

    prep_kernel<<<16, 256, 0, stream>>>(W, Wb, counts, n);

    hist_kernel<<<(E + 255) / 256, 256, 0, stream>>>(e, counts, E);

    gemm_kernel<<<(n + 31) / 32, 256, 0, stream>>>(x, Wb, b, y, n);

    scan_partial_kernel<<<nb, 256, 0, stream>>>(counts, row_start, partials, n);
    scan_add_kernel<<<nb, 256, 0, stream>>>(row_start, partials, cursor, n, nb);
    place_kernel<<<(E + 255) / 256, 256, 0, stream>>>(e, cursor, sorted_src, E);

    seg_max_finalize_kernel<<<(n + 3) / 4, 256, 0, stream>>>(
        row_start, sorted_src, (const unsigned int*)y, x, g, rb, out, n);
}

// Round 12
// 190.785 us; speedup vs baseline: 1.0019x; 1.0019x over previous
//
#include <hip/hip_runtime.h>
#include <hip/hip_bf16.h>

// Problem constants
#define D 128
#define EPS 1e-5f

typedef __bf16 bf16x8 __attribute__((ext_vector_type(8)));
typedef __bf16 bf16x4 __attribute__((ext_vector_type(4)));
typedef float  f32x4  __attribute__((ext_vector_type(4)));
typedef float  f32x2  __attribute__((ext_vector_type(2)));   // clang vector: OK for nontemporal builtin

// ---------------------------------------------------------------------------
// LAUNCH ORDER (round 11): prep -> hist -> scan_partial -> scan_add -> place
// -> gemm -> seg_max.  The harness's 288 MB 0xAA poison fill leaves ~45 us of
// dirty-writeback draining to HBM at iteration start; the CSR chain
// (latency/atomic-bound, <20 MB traffic) absorbs that shadow, and the
// BW-hungry gemm runs after it has drained.  Pure reorder — all deps hold.
// ---------------------------------------------------------------------------

// ---------------------------------------------------------------------------
// Kernel 1 (prep): convert W (f32) -> Wb (bf16, 32 KB) AND zero counts.
// ---------------------------------------------------------------------------
__global__ __launch_bounds__(256) void prep_kernel(
    const float* __restrict__ W, __bf16* __restrict__ Wb,
    int* __restrict__ counts, int n)
{
    const int tid = blockIdx.x * 256 + threadIdx.x;   // 0..4095

    if (tid < 4096) {
        float4 v = ((const float4*)W)[tid];
        bf16x4 h;
        h[0] = (__bf16)v.x; h[1] = (__bf16)v.y;
        h[2] = (__bf16)v.z; h[3] = (__bf16)v.w;
        ((bf16x4*)Wb)[tid] = h;
    }
    for (int i = tid; i < n; i += 4096)
        counts[i] = 0;
}

// ---------------------------------------------------------------------------
// Kernel 2: dst-degree histogram (runs inside the poison writeback shadow;
// atomic-latency-bound, low BW need).
// ---------------------------------------------------------------------------
__global__ __launch_bounds__(256) void hist_kernel(
    const int* __restrict__ e, int* __restrict__ counts, int E)
{
    int i = blockIdx.x * 256 + threadIdx.x;
    if (i < E) {
        int2 ed = ((const int2*)e)[i];
        atomicAdd(&counts[ed.y], 1);
    }
}

// ---------------------------------------------------------------------------
// CSR build, step 2a: per-block exclusive scan (256 elems/block).
// ---------------------------------------------------------------------------
__global__ __launch_bounds__(256) void scan_partial_kernel(
    const int* __restrict__ counts, int* __restrict__ row_start,
    int* __restrict__ partials, int n)
{
    __shared__ int s[256];
    const int tid = threadIdx.x;
    const int i = blockIdx.x * 256 + tid;
    int v = (i < n) ? counts[i] : 0;
    s[tid] = v;
    __syncthreads();
    for (int off = 1; off < 256; off <<= 1) {
        int add = (tid >= off) ? s[tid - off] : 0;
        __syncthreads();
        s[tid] += add;
        __syncthreads();
    }
    if (i < n) row_start[i] = s[tid] - v;        // relative exclusive
    if (tid == 255) partials[blockIdx.x] = s[255];
}

// ---------------------------------------------------------------------------
// CSR build, step 2b: every block re-scans partials in LDS, takes its own
// exclusive prefix, adds to its rows. Writes sentinel row_start[n] = E.
// ---------------------------------------------------------------------------
__global__ __launch_bounds__(256) void scan_add_kernel(
    int* __restrict__ row_start, const int* __restrict__ partials,
    int* __restrict__ cursor, int n, int nb)
{
    __shared__ int s[256];
    const int tid = threadIdx.x;
    int v = (tid < nb) ? partials[tid] : 0;
    s[tid] = v;
    __syncthreads();
    for (int off = 1; off < 256; off <<= 1) {
        int add = (tid >= off) ? s[tid - off] : 0;
        __syncthreads();
        s[tid] += add;
        __syncthreads();
    }
    int off0 = (blockIdx.x == 0) ? 0 : s[blockIdx.x - 1];  // exclusive prefix

    if (blockIdx.x == 0 && tid == 0)
        row_start[n] = s[255];                    // sentinel: total edge count

    int i = blockIdx.x * 256 + tid;
    if (i < n) {
        int val = row_start[i] + off0;
        row_start[i] = val;
        cursor[i]    = val;
    }
}

// ---------------------------------------------------------------------------
// CSR build, step 3: place each edge's src (uint16: n < 65536) into its
// dst segment. Order nondeterministic; max is order-independent -> bit-exact.
// ---------------------------------------------------------------------------
__global__ __launch_bounds__(256) void place_kernel(
    const int* __restrict__ e, int* __restrict__ cursor,
    unsigned short* __restrict__ sorted_src, int E)
{
    int i = blockIdx.x * 256 + threadIdx.x;
    if (i < E) {
        int2 ed = ((const int2*)e)[i];             // (src, dst)
        int pos = atomicAdd(&cursor[ed.y], 1);
        sorted_src[pos] = (unsigned short)ed.x;
    }
}

// ---------------------------------------------------------------------------
// Kernel 6: y_bf16 = relu(x @ W^T + b) via MFMA (round-10 core, now launched
// AFTER the CSR chain so the poison writeback has drained).
// 16x64 wave tiles, all loads register-hoisted, LDS-staged coalesced store.
// C/D layout (m89-verified): col = lane&15, row = (lane>>4)*4 + reg.
// ---------------------------------------------------------------------------
__global__ __launch_bounds__(256) void gemm_kernel(
    const float* __restrict__ x, const __bf16* __restrict__ Wb,
    const float* __restrict__ b, __bf16* __restrict__ y, int n)
{
    __shared__ __attribute__((aligned(16))) __bf16 ys[32][136];

    const int tid  = threadIdx.x;
    const int w    = tid >> 6;
    const int l    = tid & 63;
    const int lr   = l & 15;
    const int lk   = l >> 4;                    // 0..3
    const int brow0 = (w & 1) * 16;             // block-local row base of wave
    const int row0 = blockIdx.x * 32 + brow0;   // global row base of wave
    const int col0 = (w >> 1) * 64;

    int ar = row0 + lr;
    if (ar >= n) ar = n - 1;                    // clamp; stores are guarded
    const float* xr = x + (size_t)ar * D;

    // ---- issue ALL loads up front (independent; deep MLP) ----
    float4 xv[8];
#pragma unroll
    for (int ks = 0; ks < 4; ks++) {
        xv[2 * ks]     = *(const float4*)(xr + ks * 32 + lk * 8);
        xv[2 * ks + 1] = *(const float4*)(xr + ks * 32 + lk * 8 + 4);
    }
    bf16x8 wf[4][4];
#pragma unroll
    for (int ct = 0; ct < 4; ct++)
#pragma unroll
        for (int ks = 0; ks < 4; ks++)
            wf[ct][ks] = *(const bf16x8*)
                (Wb + (size_t)(col0 + ct * 16 + lr) * D + ks * 32 + lk * 8);

    // ---- convert a-frags in registers ----
    bf16x8 a[4];
#pragma unroll
    for (int ks = 0; ks < 4; ks++) {
        bf16x8 t;
        t[0] = (__bf16)xv[2 * ks].x;     t[1] = (__bf16)xv[2 * ks].y;
        t[2] = (__bf16)xv[2 * ks].z;     t[3] = (__bf16)xv[2 * ks].w;
        t[4] = (__bf16)xv[2 * ks + 1].x; t[5] = (__bf16)xv[2 * ks + 1].y;
        t[6] = (__bf16)xv[2 * ks + 1].z; t[7] = (__bf16)xv[2 * ks + 1].w;
        a[ks] = t;
    }

    // ---- MFMA chain (4 independent accumulators) ----
    f32x4 acc[4];
#pragma unroll
    for (int ct = 0; ct < 4; ct++) acc[ct] = (f32x4){0.f, 0.f, 0.f, 0.f};
#pragma unroll
    for (int ks = 0; ks < 4; ks++)
#pragma unroll
        for (int ct = 0; ct < 4; ct++)
            acc[ct] = __builtin_amdgcn_mfma_f32_16x16x32_bf16(
                a[ks], wf[ct][ks], acc[ct], 0, 0, 0);

    // ---- bias + relu into LDS tile ----
#pragma unroll
    for (int ct = 0; ct < 4; ct++) {
        const int c = col0 + ct * 16 + lr;
        const float bias = b[c];
#pragma unroll
        for (int reg = 0; reg < 4; reg++)
            ys[brow0 + lk * 4 + reg][c] = (__bf16)fmaxf(acc[ct][reg] + bias, 0.f);
    }
    __syncthreads();

    // ---- coalesced store: 32 rows x 256 B; thread t -> row t>>3, 32 B seg ----
    {
        const int r = tid >> 3;
        const int s = tid & 7;
        const int gr = blockIdx.x * 32 + r;
        if (gr < n) {
            const float4* src = (const float4*)&ys[r][s * 16];
            float4 v0 = src[0];
            float4 v1 = src[1];
            float4* dst = (float4*)(y + (size_t)gr * D + s * 16);
            dst[0] = v0;
            dst[1] = v1;
        }
    }
}

// ---------------------------------------------------------------------------
// Kernel 7 (fused): per-dst gather-max over CSR segment (y in bf16), then
// h = x + agg; RMSNorm; out = h * rsqrt(mean(h^2)+eps) * g + rb.
// One 64-lane wave per row; lane holds one uint = 2 bf16 (256 B/row gather).
// bf16 -> f32 is an exact <<16; max over non-negative bf16 is exact.
// `out` stored non-temporally (never re-read; keep y/x resident instead).
// ---------------------------------------------------------------------------
__global__ __launch_bounds__(256) void seg_max_finalize_kernel(
    const int* __restrict__ row_start, const unsigned short* __restrict__ ssrc,
    const unsigned int* __restrict__ ybu, const float* __restrict__ x,
    const float* __restrict__ g, const float* __restrict__ rb,
    float* __restrict__ out, int n)
{
    int row  = blockIdx.x * 4 + (threadIdx.x >> 6);
    int lane = threadIdx.x & 63;
    if (row >= n) return;

    const int start = row_start[row];
    const int end   = row_start[row + 1];

    float mx = 0.f, my = 0.f;
    int k = start;
    const int end8 = start + ((end - start) & ~7);
    for (; k < end8; k += 8) {
        int s0 = ssrc[k + 0], s1 = ssrc[k + 1], s2 = ssrc[k + 2], s3 = ssrc[k + 3];
        int s4 = ssrc[k + 4], s5 = ssrc[k + 5], s6 = ssrc[k + 6], s7 = ssrc[k + 7];
        unsigned int u0 = ybu[(size_t)s0 * 64 + lane];
        unsigned int u1 = ybu[(size_t)s1 * 64 + lane];
        unsigned int u2 = ybu[(size_t)s2 * 64 + lane];
        unsigned int u3 = ybu[(size_t)s3 * 64 + lane];
        unsigned int u4 = ybu[(size_t)s4 * 64 + lane];
        unsigned int u5 = ybu[(size_t)s5 * 64 + lane];
        unsigned int u6 = ybu[(size_t)s6 * 64 + lane];
        unsigned int u7 = ybu[(size_t)s7 * 64 + lane];
        mx = fmaxf(mx, fmaxf(fmaxf(__uint_as_float(u0 << 16), __uint_as_float(u1 << 16)),
                             fmaxf(__uint_as_float(u2 << 16), __uint_as_float(u3 << 16))));
        mx = fmaxf(mx, fmaxf(fmaxf(__uint_as_float(u4 << 16), __uint_as_float(u5 << 16)),
                             fmaxf(__uint_as_float(u6 << 16), __uint_as_float(u7 << 16))));
        my = fmaxf(my, fmaxf(fmaxf(__uint_as_float(u0 & 0xffff0000u), __uint_as_float(u1 & 0xffff0000u)),
                             fmaxf(__uint_as_float(u2 & 0xffff0000u), __uint_as_float(u3 & 0xffff0000u))));
        my = fmaxf(my, fmaxf(fmaxf(__uint_as_float(u4 & 0xffff0000u), __uint_as_float(u5 & 0xffff0000u)),
                             fmaxf(__uint_as_float(u6 & 0xffff0000u), __uint_as_float(u7 & 0xffff0000u))));
    }
    for (; k < end; k++) {
        int s0 = ssrc[k];
        unsigned int u0 = ybu[(size_t)s0 * 64 + lane];
        mx = fmaxf(mx, __uint_as_float(u0 << 16));
        my = fmaxf(my, __uint_as_float(u0 & 0xffff0000u));
    }

    float2 xv = ((const float2*)(x + (size_t)row * D))[lane];
    float hx = xv.x + mx;
    float hy = xv.y + my;

    float ss = hx * hx + hy * hy;
#pragma unroll
    for (int off = 1; off < 64; off <<= 1) ss += __shfl_xor(ss, off);

    float inv = rsqrtf(ss * (1.0f / (float)D) + EPS);

    float2 gv = ((const float2*)g)[lane];
    float2 rv = ((const float2*)rb)[lane];
    f32x2 o;
    o[0] = hx * inv * gv.x + rv.x;
    o[1] = hy * inv * gv.y + rv.y;
    __builtin_nontemporal_store(o, (f32x2*)(out + (size_t)row * D) + lane);
}

// ---------------------------------------------------------------------------
extern "C" void kernel_launch(void* const* d_in, const int* in_sizes, int n_in,
                              void* d_out, int out_size, void* d_ws, size_t ws_size,
                              hipStream_t stream)
{
    const float* x  = (const float*)d_in[0];
    const int*   e  = (const int*)  d_in[1];
    const float* W  = (const float*)d_in[2];
    const float* b  = (const float*)d_in[3];
    const float* g  = (const float*)d_in[4];
    const float* rb = (const float*)d_in[5];
    float* out = (float*)d_out;

    const int n = in_sizes[0] / D;     // 40000 nodes
    const int E = in_sizes[1] / 2;     // 640000 edges

    // Workspace layout (256B-aligned offsets)
    char* ws = (char*)d_ws;
    __bf16* y        = (__bf16*)(ws);                      // 10,240,000 B
    int*   counts    = (int*)  (ws + 10240000);            //    160,000 B
    int*   row_start = (int*)  (ws + 10400000);            //    160,004 B (+sentinel)
    int*   cursor    = (int*)  (ws + 10560256);            //    160,000 B
    unsigned short* sorted_src = (unsigned short*)(ws + 10720256); // 1,280,000 B
    int*   partials  = (int*)  (ws + 12000256);            //      1,024 B
    __bf16* Wb       = (__bf16*)(ws + 12001536);           //     32,768 B

    const int nb = (n + 255) / 256;                 // 157 (must be <= 256)

    // --- shadow-absorbing, latency-bound CSR chain first ---
    prep_kernel<<<16, 256, 0, stream>>>(W, Wb, counts, n);
    hist_kernel<<<(E + 255) / 256, 256, 0, stream>>>(e, counts, E);
    scan_partial_kernel<<<nb, 256, 0, stream>>>(counts, row_start, partials, n);
    scan_add_kernel<<<nb, 256, 0, stream>>>(row_start, partials, cursor, n, nb);
    place_kernel<<<(E + 255) / 256, 256, 0, stream>>>(e, cursor, sorted_src, E);

    // --- bandwidth-hungry kernels after the poison writeback has drained ---
    gemm_kernel<<<(n + 31) / 32, 256, 0, stream>>>(x, Wb, b, y, n);

    seg_max_finalize_kernel<<<(n + 3) / 4, 256, 0, stream>>>(
        row_start, sorted_src, (const unsigned int*)y, x, g, rb, out, n);
}